// Round 9
// baseline (131.793 us; speedup 1.0000x reference)
//
#include <hip/hip_runtime.h>
#include <float.h>
#include <math.h>

#define NB 32
#define LD 512
#define LP 4096
#define HD 128
#define PV 26

// One block per batch (32 blocks x 1024 threads). Everything in-block:
// scores (2-way K split), masked row softmax, col-max, protein softmax via
// histogram counts, d_vec gather, p_vec, MLP. No workspace, no cross-block
// traffic, no fences, no atomics to global.
__global__ __launch_bounds__(1024)
void k_all(const int* __restrict__ drug_ids, const int* __restrict__ prot_ids,
           const float* __restrict__ drug_emb, const float* __restrict__ prot_emb,
           const float* __restrict__ W1, const float* __restrict__ b1,
           const float* __restrict__ W2, const float* __restrict__ b2,
           float* __restrict__ out) {
    int b = blockIdx.x;
    int t = threadIdx.x;
    int wave = t >> 6, lane = t & 63;
    int row = t & 511, kh = t >> 9;          // kh uniform per wave

    __shared__ float SH[512 * 27];           // 55.3 KB: shalf, later part/comb/...
    __shared__ float att[LD];
    __shared__ int   sids[LD];
    __shared__ int   cnt4[4][32];
    __shared__ int   scnt[32];
    __shared__ float redm[8], reds[8];
    __shared__ float cpart[8][27];
    __shared__ float sInvP;

    float* part  = SH;                       // [8][128]   (aliases dead shalf)
    float* comb  = SH + 1024;                // [256]
    float* hpart = SH + 1280;                // [4][64]
    float* ew    = SH + 1536;                // [32]

    // ---- S0: zero hist, stage drug ids ----
    if (t < 128) ((int*)cnt4)[t] = 0;
    if (t < LD) sids[t] = drug_ids[b * LD + t];
    __syncthreads();

    // histogram of prot_ids: 4096 ids, exactly 1 int4 per thread
    {
        int4 v = reinterpret_cast<const int4*>(prot_ids + b * LP)[t];
        int sub = wave & 3;
        atomicAdd(&cnt4[sub][v.x], 1);
        atomicAdd(&cnt4[sub][v.y], 1);
        atomicAdd(&cnt4[sub][v.z], 1);
        atomicAdd(&cnt4[sub][v.w], 1);
    }

    // scores: thread (row,kh) covers k in [kh*64, kh*64+64)
    const float* __restrict__ A =
        drug_emb + (size_t)drug_ids[b * LD + row] * HD + kh * 64;
    float4 a[16];
    #pragma unroll
    for (int i = 0; i < 16; ++i) a[i] = reinterpret_cast<const float4*>(A)[i];

    const float* __restrict__ Bk = prot_emb + kh * 64;
    float s[PV];
    #pragma unroll
    for (int v = 0; v < PV; ++v) s[v] = 0.f;
    #pragma unroll
    for (int i = 0; i < 16; ++i) {
        float4 av = a[i];
        #pragma unroll
        for (int v = 0; v < PV; ++v) {
            float4 p = reinterpret_cast<const float4*>(Bk + v * HD)[i];
            s[v] = fmaf(av.x, p.x, fmaf(av.y, p.y,
                   fmaf(av.z, p.z, fmaf(av.w, p.w, s[v]))));
        }
    }

    __syncthreads();                          // S1: cnt4 done, SH writable
    if (t < 32) scnt[t] = cnt4[0][t] + cnt4[1][t] + cnt4[2][t] + cnt4[3][t];
    if (kh == 1) {
        #pragma unroll
        for (int v = 0; v < PV; ++v) SH[row * 27 + v] = s[v];
    }
    __syncthreads();                          // S2: scnt + half-panel ready

    float r = -FLT_MAX;
    if (kh == 0) {
        #pragma unroll
        for (int v = 0; v < PV; ++v) s[v] += SH[row * 27 + v];
        #pragma unroll
        for (int v = 0; v < PV; ++v)
            if (scnt[v] > 0) r = fmaxf(r, s[v]);
        float m = r;
        #pragma unroll
        for (int off = 32; off; off >>= 1) m = fmaxf(m, __shfl_xor(m, off, 64));
        if (lane == 0) redm[wave] = m;
    }
    __syncthreads();                          // S3: redm ready; SH reads done

    float gm = fmaxf(fmaxf(fmaxf(redm[0], redm[1]), fmaxf(redm[2], redm[3])),
                     fmaxf(fmaxf(redm[4], redm[5]), fmaxf(redm[6], redm[7])));
    if (kh == 0) {
        float e = __expf(r - gm);
        att[row] = e;
        float ssum = e;
        #pragma unroll
        for (int off = 32; off; off >>= 1) ssum += __shfl_xor(ssum, off, 64);
        if (lane == 0) reds[wave] = ssum;
        // per-wave col maxima (64 rows each)
        #pragma unroll
        for (int v = 0; v < PV; ++v) {
            float cm = s[v];
            #pragma unroll
            for (int off = 32; off; off >>= 1)
                cm = fmaxf(cm, __shfl_xor(cm, off, 64));
            if (lane == 0) cpart[wave][v] = cm;
        }
    }
    __syncthreads();                          // S4: att, reds, cpart ready

    // wave 8: protein softmax weights (runs before its gather share)
    if (wave == 8) {
        float cmx = -FLT_MAX; int c = 0;
        if (lane < PV) {
            #pragma unroll
            for (int w8 = 0; w8 < 8; ++w8) cmx = fmaxf(cmx, cpart[w8][lane]);
            c = scnt[lane];
        }
        float m0 = (c > 0) ? cmx : -FLT_MAX;
        float M2 = m0;
        #pragma unroll
        for (int off = 32; off; off >>= 1) M2 = fmaxf(M2, __shfl_xor(M2, off, 64));
        float w = (c > 0) ? (float)c * __expf(cmx - M2) : 0.f;
        float S = w;
        #pragma unroll
        for (int off = 32; off; off >>= 1) S += __shfl_xor(S, off, 64);
        if (lane < 32) ew[lane] = (lane < PV) ? w : 0.f;
        if (lane == 0) sInvP = 1.f / S;
    }

    // d_vec gather: 8 groups x 128 h, 64 L2-hot rows each (part aliases SH)
    {
        int g = t >> 7, h = t & 127;
        float acc = 0.f;
        #pragma unroll 8
        for (int i = 0; i < 64; ++i) {
            int l = g * 64 + i;
            acc = fmaf(att[l], drug_emb[(size_t)sids[l] * HD + h], acc);
        }
        part[g * 128 + h] = acc;
    }
    __syncthreads();                          // S5: part, ew, sInvP ready

    if (t < HD) {
        float invD = 1.f / (reds[0] + reds[1] + reds[2] + reds[3] +
                            reds[4] + reds[5] + reds[6] + reds[7]);
        float d = 0.f;
        #pragma unroll
        for (int g = 0; g < 8; ++g) d += part[g * 128 + t];
        comb[t] = d * invD;
    } else if (t < 2 * HD) {
        int h = t - HD;
        float p = 0.f;
        #pragma unroll
        for (int v = 0; v < PV; ++v)
            p = fmaf(ew[v], prot_emb[v * HD + h], p);
        comb[t] = p * sInvP;
    }
    __syncthreads();                          // S6: comb ready

    if (t < 256) {
        int j = t & 63, seg = t >> 6;
        float acc = 0.f;
        #pragma unroll
        for (int k = 0; k < 64; ++k) {
            int kk = seg * 64 + k;
            acc = fmaf(comb[kk], W1[kk * 64 + j], acc);
        }
        hpart[seg * 64 + j] = acc;
    }
    __syncthreads();                          // S7: hpart ready

    if (t < 64) {
        float hj = b1[t] + hpart[t] + hpart[64 + t] + hpart[128 + t] + hpart[192 + t];
        hj = fmaxf(hj, 0.f);
        float o = hj * W2[t];
        #pragma unroll
        for (int off = 32; off; off >>= 1) o += __shfl_xor(o, off, 64);
        if (t == 0) out[b] = o + b2[0];
    }
}

extern "C" void kernel_launch(void* const* d_in, const int* in_sizes, int n_in,
                              void* d_out, int out_size, void* d_ws, size_t ws_size,
                              hipStream_t stream) {
    const int*   drug_ids = (const int*)d_in[0];
    const int*   prot_ids = (const int*)d_in[1];
    const float* drug_emb = (const float*)d_in[2];
    const float* prot_emb = (const float*)d_in[3];
    const float* W1 = (const float*)d_in[4];
    const float* b1 = (const float*)d_in[5];
    const float* W2 = (const float*)d_in[6];
    const float* b2 = (const float*)d_in[7];
    float* out = (float*)d_out;

    k_all<<<NB, 1024, 0, stream>>>(drug_ids, prot_ids, drug_emb, prot_emb,
                                   W1, b1, W2, b2, out);
}

// Round 10
// 16.500 us; speedup vs baseline: 7.9873x; 7.9873x over previous
//
#include <hip/hip_runtime.h>
#include <float.h>
#include <math.h>

#define NB 32
#define LD 512
#define LP 4096
#define HD 128
#define PV 26
#define MAGIC 0x13579BDF
#define QS 1733   // padded per-q LDS slice: 64*27+5; 1733%32=5 -> q-slices bank-staggered
// ws layout (float index):
//   flag    int[256]       @ 0      (self-resetting; never memset)
//   ws_m    float[256]     @ 256
//   ws_den  float[256]     @ 512
//   ws_col  float[256*32]  @ 768
//   ws_part float[256*128] @ 8960
//   ws_hist int[256*32]    @ 41728

__device__ __forceinline__ float aloadf(float* p) { return atomicAdd(p, 0.0f); }
__device__ __forceinline__ int   aloadi(int* p)   { return atomicAdd(p, 0); }

// One node: 256 blocks x 512 threads. Block (b,chunk) runs phase A; chunks 0-6
// publish partials via device atomics in ONE batch (single drain) and raise a
// flag; chunk 7 keeps its partials in LDS, spins on the 7 flags, runs phase B
// with ILP'd atomic loads, resets flags.
__global__ __launch_bounds__(512)
void k_fused(const int* __restrict__ drug_ids, const int* __restrict__ prot_ids,
             const float* __restrict__ drug_emb, const float* __restrict__ prot_emb,
             const float* __restrict__ W1, const float* __restrict__ b1,
             const float* __restrict__ W2, const float* __restrict__ b2,
             float* __restrict__ out, float* __restrict__ wsf) {
    int*   flag    = (int*)wsf;
    float* ws_m    = wsf + 256;
    float* ws_den  = wsf + 512;
    float* ws_col  = wsf + 768;
    float* ws_part = wsf + 8960;
    int*   ws_hist = (int*)(wsf + 41728);

    int t = threadIdx.x;
    int wid = t >> 6, lane = t & 63;
    int b = blockIdx.x >> 3, chunk = blockIdx.x & 7;
    int b8 = b << 3;
    int q = __builtin_amdgcn_readfirstlane(wid);
    int l = chunk * 64 + lane;

    __shared__ float red[8 * QS];      // 55.4 KB
    __shared__ float ev[64];
    __shared__ unsigned wor[8];
    __shared__ int   hist8[8][32];     // per-wave sub-histograms
    __shared__ int   histL[32];
    __shared__ float partL[128], cpartL[32], sMD[2];
    __shared__ float sscale[8], ew[32], comb[2 * HD], hpart[4][64];
    __shared__ float sInvD, sInvP;

    // ---------------- Phase A ----------------
    if (t < 256) ((int*)hist8)[t] = 0;

    // presence mask over all 4096 ids (8/thread)
    const int4* pid4 = reinterpret_cast<const int4*>(prot_ids + b * LP);
    int4 i0 = pid4[t], i1 = pid4[t + 512];
    unsigned pm = (1u << i0.x) | (1u << i0.y) | (1u << i0.z) | (1u << i0.w)
                | (1u << i1.x) | (1u << i1.y) | (1u << i1.z) | (1u << i1.w);
    #pragma unroll
    for (int off = 32; off; off >>= 1) pm |= __shfl_xor(pm, off, 64);
    if (lane == 0) wor[q] = pm;

    // A sixteenth-row preload (16 k-floats; reused for d_vec partial)
    const float* __restrict__ A =
        drug_emb + (size_t)drug_ids[b * LD + l] * HD + q * 16;
    float4 a[4];
    #pragma unroll
    for (int i = 0; i < 4; ++i) a[i] = reinterpret_cast<const float4*>(A)[i];

    __syncthreads();   // hist8 zeroed, wor visible

    // own-slice histogram (512 ids, 1/thread, per-wave sub-hist)
    atomicAdd(&hist8[wid][prot_ids[b * LP + chunk * 512 + t]], 1);

    const float* __restrict__ Bq = prot_emb + q * 16;
    float s[PV];
    #pragma unroll
    for (int v = 0; v < PV; ++v) s[v] = 0.f;
    #pragma unroll
    for (int i = 0; i < 4; ++i) {
        float4 av = a[i];
        #pragma unroll
        for (int v = 0; v < PV; ++v) {
            float4 p = reinterpret_cast<const float4*>(Bq + v * HD)[i];
            s[v] = fmaf(av.x, p.x, fmaf(av.y, p.y,
                   fmaf(av.z, p.z, fmaf(av.w, p.w, s[v]))));
        }
    }
    #pragma unroll
    for (int v = 0; v < PV; ++v) red[q * QS + lane * 27 + v] = s[v];
    __syncthreads();

    unsigned msk = wor[0] | wor[1] | wor[2] | wor[3]
                 | wor[4] | wor[5] | wor[6] | wor[7];

    // K-reduce 8 slices into slice 0
    for (int o = t; o < 64 * PV; o += 512) {
        int l2 = o / PV, v = o - l2 * PV;
        int idx = l2 * 27 + v;
        red[idx] = red[idx]           + red[QS + idx]     + red[2 * QS + idx]
                 + red[3 * QS + idx]  + red[4 * QS + idx] + red[5 * QS + idx]
                 + red[6 * QS + idx]  + red[7 * QS + idx];
    }
    __syncthreads();

    float pub_m = 0.f, pub_den = 0.f, pub_cmx = -FLT_MAX;
    if (wid == 0) {
        float r = -FLT_MAX;
        #pragma unroll
        for (int v = 0; v < PV; ++v)
            if ((msk >> v) & 1) r = fmaxf(r, red[lane * 27 + v]);
        float m = r;
        #pragma unroll
        for (int off = 32; off; off >>= 1) m = fmaxf(m, __shfl_xor(m, off, 64));
        float e = __expf(r - m);
        ev[lane] = e;
        float den = e;
        #pragma unroll
        for (int off = 32; off; off >>= 1) den += __shfl_xor(den, off, 64);
        pub_m = m; pub_den = den;
    } else if (wid == 1 && lane < PV) {
        float cmx = -FLT_MAX;
        for (int r = 0; r < 64; ++r) cmx = fmaxf(cmx, red[r * 27 + lane]);
        pub_cmx = cmx;
    }
    __syncthreads();   // ev ready; red free; (no pending atomics -> cheap)

    // d_vec partial: red[q][lane][c] = e_lane * a_c  (h = q*16+c)
    float myE = ev[lane];
    #pragma unroll
    for (int i = 0; i < 4; ++i) {
        red[q * QS + lane * 27 + 4 * i + 0] = myE * a[i].x;
        red[q * QS + lane * 27 + 4 * i + 1] = myE * a[i].y;
        red[q * QS + lane * 27 + 4 * i + 2] = myE * a[i].z;
        red[q * QS + lane * 27 + 4 * i + 3] = myE * a[i].w;
    }
    __syncthreads();

    float psum = 0.f;
    if (t < 128) {       // (t>>4)*16 + (t&15) == t : ws_part index is t
        int qq = t >> 4, c = t & 15;
        for (int r = 0; r < 64; ++r) psum += red[qq * QS + r * 27 + c];
    }
    int hsum = 0;
    if (t < 32) {
        #pragma unroll
        for (int w8 = 0; w8 < 8; ++w8) hsum += hist8[w8][t];
        histL[t] = hsum;
    }

    if (chunk != 7) {
        // single publish batch -> one drain at the barrier below
        if (t < 128) atomicExch(&ws_part[(b8 + chunk) * 128 + t], psum);
        if (t < 32)  atomicExch(&ws_hist[(b8 + chunk) * 32 + t], hsum);
        if (wid == 0 && lane == 0) {
            atomicExch(&ws_m[b8 + chunk], pub_m);
            atomicExch(&ws_den[b8 + chunk], pub_den);
        }
        if (wid == 1 && lane < PV)
            atomicExch(&ws_col[(b8 + chunk) * 32 + lane], pub_cmx);
        __syncthreads();             // drains vmcnt -> publishes visible
        if (t == 0) atomicExch(&flag[b8 + chunk], MAGIC);
        return;
    }

    // chunk-7: stash locals (no global publishes on the critical path)
    if (t < 128) partL[t] = psum;
    if (wid == 0 && lane == 0) { sMD[0] = pub_m; sMD[1] = pub_den; }
    if (wid == 1 && lane < PV) cpartL[lane] = pub_cmx;

    // ---------------- spin for 7 siblings ----------------
    if (t < 7) {
        while (aloadi(&flag[b8 + t]) != MAGIC) __builtin_amdgcn_s_sleep(1);
    }
    __syncthreads();   // flags seen + locals visible

    // ---------------- Phase B ----------------
    if (t < 8) {
        float m = (t < 7) ? aloadf(&ws_m[b8 + t]) : sMD[0];
        float M = m;
        #pragma unroll
        for (int off = 4; off; off >>= 1) M = fmaxf(M, __shfl_xor(M, off, 8));
        float sc = __expf(m - M);
        float den = (t < 7) ? aloadf(&ws_den[b8 + t]) : sMD[1];
        float dd = sc * den;
        float D = dd;
        #pragma unroll
        for (int off = 4; off; off >>= 1) D += __shfl_xor(D, off, 8);
        sscale[t] = sc;
        if (t == 0) sInvD = 1.f / D;
    } else if (wid == 1) {
        int v = lane;
        float cmx = -FLT_MAX; int c = 0;
        if (v < PV) {
            float cl[7]; int hl[7];
            #pragma unroll
            for (int c8 = 0; c8 < 7; ++c8) {     // 14 independent atomic loads
                cl[c8] = aloadf(&ws_col[(b8 + c8) * 32 + v]);
                hl[c8] = aloadi(&ws_hist[(b8 + c8) * 32 + v]);
            }
            cmx = cpartL[v]; c = histL[v];
            #pragma unroll
            for (int c8 = 0; c8 < 7; ++c8) { cmx = fmaxf(cmx, cl[c8]); c += hl[c8]; }
        }
        float m0 = (c > 0) ? cmx : -FLT_MAX;
        float M2 = m0;
        #pragma unroll
        for (int off = 32; off; off >>= 1) M2 = fmaxf(M2, __shfl_xor(M2, off, 64));
        float w = (c > 0) ? (float)c * __expf(cmx - M2) : 0.f;
        float S = w;
        #pragma unroll
        for (int off = 32; off; off >>= 1) S += __shfl_xor(S, off, 64);
        if (v < 32) ew[v] = (v < PV) ? w : 0.f;
        if (lane == 0) sInvP = 1.f / S;
    }
    __syncthreads();

    if (t < HD) {
        float pl[7];
        #pragma unroll
        for (int c8 = 0; c8 < 7; ++c8)           // 7 independent atomic loads
            pl[c8] = aloadf(&ws_part[(b8 + c8) * 128 + t]);
        float d = sscale[7] * partL[t];
        #pragma unroll
        for (int c8 = 0; c8 < 7; ++c8) d = fmaf(sscale[c8], pl[c8], d);
        comb[t] = d * sInvD;
    } else if (t < 2 * HD) {
        int h = t - HD;
        float p = 0.f;
        #pragma unroll
        for (int v = 0; v < PV; ++v)
            p = fmaf(ew[v], prot_emb[v * HD + h], p);
        comb[t] = p * sInvP;
    }
    __syncthreads();

    // MLP 256->64 (4-way K split) -> relu -> 64->1
    if (t < 256) {
        int j = t & 63, seg = t >> 6;
        float acc = 0.f;
        #pragma unroll
        for (int k = 0; k < 64; ++k) {
            int kk = seg * 64 + k;
            acc = fmaf(comb[kk], W1[kk * 64 + j], acc);
        }
        hpart[seg][j] = acc;
    }
    __syncthreads();
    if (t < 64) {
        float hj = b1[t] + hpart[0][t] + hpart[1][t] + hpart[2][t] + hpart[3][t];
        hj = fmaxf(hj, 0.f);
        float o = hj * W2[t];
        #pragma unroll
        for (int off = 32; off; off >>= 1) o += __shfl_xor(o, off, 64);
        if (t == 0) out[b] = o + b2[0];
    }
    __syncthreads();
    // self-clean flags for the next replay (no memset node needed)
    if (t < 7) atomicExch(&flag[b8 + t], 0);
}

extern "C" void kernel_launch(void* const* d_in, const int* in_sizes, int n_in,
                              void* d_out, int out_size, void* d_ws, size_t ws_size,
                              hipStream_t stream) {
    const int*   drug_ids = (const int*)d_in[0];
    const int*   prot_ids = (const int*)d_in[1];
    const float* drug_emb = (const float*)d_in[2];
    const float* prot_emb = (const float*)d_in[3];
    const float* W1 = (const float*)d_in[4];
    const float* b1 = (const float*)d_in[5];
    const float* W2 = (const float*)d_in[6];
    const float* b2 = (const float*)d_in[7];
    float* out = (float*)d_out;
    float* wsf = (float*)d_ws;

    k_fused<<<NB * 8, 512, 0, stream>>>(drug_ids, prot_ids, drug_emb, prot_emb,
                                        W1, b1, W2, b2, out, wsf);
}